// Round 7
// baseline (291.531 us; speedup 1.0000x reference)
//
#include <hip/hip_runtime.h>

// VectorQuantizer on MI355X — round 7: permuted-codebook coalesced MFMA scan,
// mega-fused (z-staging + scan + argmin + gather + loss in ONE kernel).
// z: [32,256,32,32] fp32; codebook: [1024,256] fp32; N=32768, K=1024, C=256.
// dist = |e|^2 - 2 z.e. Single-pass f16 MFMA approx; tokens with approx top-2
// gap <= DELTA get exact fp32 rescan + full fix-up (out row, counts, lsum).
// Loss via identity: sum(z-q)^2 = sum|z|^2 + sum dist(n, k*).
//
// ehp layout (MFMA A-frag order): half8 chunk q8 = bi*64 + lane, bi = (kt*8+ks)*4+mt:
//   ehp[q8*8 + j] = f16(cb[kt*64 + mt*16 + (lane&15)][ (lane>>4)*8 + ks*32 + j ])
// -> scan's A-loads are lane-linear 1KB coalesced L2 streams.
//
// ws layout (bytes):
//   ehp     @ 0        _Float16[512*512] (524288)
//   enorm   @ 524288   float[1024]
//   idx     @ 528384   int[32768]
//   dmin    @ 659456   float[32768]   approx dist of chosen code (for rescue fixup)
//   counts  @ 790528   int[1024]
//   lsum    @ 794624   float
//   nflag   @ 794688   int
//   flag    @ 794752   int[32768]

#define BETA  0.25f
#define DELTA 0.3f

typedef _Float16 half8 __attribute__((ext_vector_type(8)));
typedef float    f32x4 __attribute__((ext_vector_type(4)));

// ---------------------------------------------------------------------------
// K1: codebook -> ehp (A-frag permuted) + exact |e|^2 + zero accums. grid 388.
// ---------------------------------------------------------------------------
__global__ __launch_bounds__(256) void vq_prep(
    const float* __restrict__ cb, _Float16* __restrict__ ehp,
    float* __restrict__ enorm, int* __restrict__ counts,
    float* __restrict__ lsum, int* __restrict__ nflag)
{
    const int tid = threadIdx.x;
    const int bid = blockIdx.x;
    if (bid < 128) {                       // permute: 32768 half8 chunks
        const int q8 = bid * 256 + tid;
        const int l  = q8 & 63;
        const int bi = q8 >> 6;            // (kt*8+ks)*4+mt, 0..511
        const int mt = bi & 3;
        const int ks = (bi >> 2) & 7;
        const int kt = bi >> 5;
        const int row  = kt * 64 + mt * 16 + (l & 15);
        const int col0 = (l >> 4) * 8 + ks * 32;
        const float4 v0 = *reinterpret_cast<const float4*>(cb + row * 256 + col0);
        const float4 v1 = *reinterpret_cast<const float4*>(cb + row * 256 + col0 + 4);
        half8 h;
        h[0] = (_Float16)v0.x; h[1] = (_Float16)v0.y; h[2] = (_Float16)v0.z; h[3] = (_Float16)v0.w;
        h[4] = (_Float16)v1.x; h[5] = (_Float16)v1.y; h[6] = (_Float16)v1.z; h[7] = (_Float16)v1.w;
        *reinterpret_cast<half8*>(ehp + (size_t)q8 * 8) = h;
    } else if (bid < 384) {                // enorm: rows 0..1023, 4 rows/block
        const int r    = (bid - 128) * 4 + (tid >> 6);
        const int lane = tid & 63;
        const float4 v = *reinterpret_cast<const float4*>(cb + r * 256 + lane * 4);
        float s = v.x * v.x + v.y * v.y + v.z * v.z + v.w * v.w;
        #pragma unroll
        for (int off = 32; off > 0; off >>= 1) s += __shfl_down(s, off);
        if (lane == 0) enorm[r] = s;
    } else {                               // zero accumulators
        counts[(bid - 384) * 256 + tid] = 0;
        if (bid == 384 && tid == 0) { *lsum = 0.0f; *nflag = 0; }
    }
}

// ---------------------------------------------------------------------------
// K2: mega-fused main. grid 512 x 512 threads (8 waves; 2 blocks/CU).
// Phase A: stage 64 tokens z fp32 -> f16 LDS (xor-swizzled) + exact |z|^2.
// Phase B: wave w scans codes [w*128,+128) in 2 tiles of 64; A-frags coalesced
//          from ehp (L2), B-frags from LDS; 4-slot register top-2, no barriers.
// Phase C: butterfly + 8-wave merge -> idx, dmin, flags, counts, loss.
// Phase D: gather cb rows (coalesced) -> LDS bounce (stride 257).
// Phase E: coalesced out write.
// ---------------------------------------------------------------------------
__global__ __launch_bounds__(512, 4) void vq_main(
    const float* __restrict__ z, const float* __restrict__ cb,
    const _Float16* __restrict__ ehp, const float* __restrict__ enorm,
    float* __restrict__ out, int* __restrict__ idx, float* __restrict__ dmin,
    int* __restrict__ counts, float* __restrict__ lsum,
    int* __restrict__ nflag, int* __restrict__ flaglist)
{
    __shared__ float qs[64 * 257];             // phase D/E bounce; bytes 0..32767 = sB
    __shared__ float znorm[64];
    __shared__ float smv1[8][64], smv2[8][64];
    __shared__ int   smi1[8][64];
    __shared__ int   sidx[64];
    _Float16* sB = (_Float16*)qs;              // 64 tokens x 256 C, swizzled

    const int tid = threadIdx.x;
    const int t   = tid & 63;                  // lane / token
    const int w   = tid >> 6;                  // wave 0..7
    const int n0  = blockIdx.x * 64;
    const float* zb = z + (n0 >> 10) * 262144 + (n0 & 1023);

    // ---- Phase A: stage z -> f16 LDS + |z|^2 ----
    if (tid < 64) znorm[tid] = 0.0f;
    __syncthreads();
    {
        float s = 0.0f;
        #pragma unroll
        for (int jj = 0; jj < 4; ++jj) {
            const int c0 = w * 32 + jj * 8;
            float f[8]; half8 h;
            #pragma unroll
            for (int j = 0; j < 8; ++j) f[j] = zb[(c0 + j) * 1024 + t];
            #pragma unroll
            for (int j = 0; j < 8; ++j) { s = fmaf(f[j], f[j], s); h[j] = (_Float16)f[j]; }
            const int gc = c0 >> 3;                           // global chunk w*4+jj
            const int sc = (gc & 24) | ((gc & 7) ^ (t & 7));  // swizzled slot
            *reinterpret_cast<half8*>(&sB[t * 256 + sc * 8]) = h;
        }
        atomicAdd(&znorm[t], s);
    }
    __syncthreads();

    // ---- Phase B: scan 128 codes ----
    const int nidx = t & 15;     // token column within 16x16
    const int g    = t >> 4;     // k-quad / code sub-row

    float m1[4] = {1e30f, 1e30f, 1e30f, 1e30f};
    float m2[4] = {1e30f, 1e30f, 1e30f, 1e30f};
    int   i1[4] = {0x7fffffff, 0x7fffffff, 0x7fffffff, 0x7fffffff};

    #pragma unroll
    for (int ct = 0; ct < 2; ++ct) {
        const int kt = w * 2 + ct;
        const _Float16* abase = ehp + (size_t)kt * 16384 + t * 8;
        f32x4 acc[4][4] = {};
        #pragma unroll
        for (int ks = 0; ks < 8; ++ks) {
            half8 a[4];
            #pragma unroll
            for (int mt = 0; mt < 4; ++mt)
                a[mt] = *reinterpret_cast<const half8*>(abase + (ks * 4 + mt) * 512);
            const int cc = ks * 4 + g;
            #pragma unroll
            for (int nt = 0; nt < 4; ++nt) {
                const int row = nt * 16 + nidx;
                const int sw  = ((cc & 24) | ((cc & 7) ^ (row & 7))) * 8;
                const half8 b = *reinterpret_cast<const half8*>(&sB[row * 256 + sw]);
                #pragma unroll
                for (int mt = 0; mt < 4; ++mt)
                    acc[mt][nt] = __builtin_amdgcn_mfma_f32_16x16x32_f16(a[mt], b, acc[mt][nt], 0, 0, 0);
            }
        }
        // fold into running top-2 (ascending code order). D: row=g*4+reg, col=lane&15.
        #pragma unroll
        for (int mt = 0; mt < 4; ++mt) {
            const int c0 = kt * 64 + mt * 16 + g * 4;
            const float4 en4 = *reinterpret_cast<const float4*>(enorm + c0);
            #pragma unroll
            for (int reg = 0; reg < 4; ++reg) {
                const float en = reg == 0 ? en4.x : reg == 1 ? en4.y : reg == 2 ? en4.z : en4.w;
                #pragma unroll
                for (int nt = 0; nt < 4; ++nt) {
                    const float d = fmaf(-2.0f, acc[mt][nt][reg], en);
                    if (d < m1[nt]) { m2[nt] = m1[nt]; m1[nt] = d; i1[nt] = c0 + reg; }
                    else            { m2[nt] = fminf(m2[nt], d); }
                }
            }
        }
    }

    // ---- Phase C: merge ----
    #pragma unroll
    for (int nt = 0; nt < 4; ++nt) {
        float a1 = m1[nt], a2 = m2[nt]; int ai = i1[nt];
        #pragma unroll
        for (int off = 16; off < 64; off <<= 1) {
            const float o1 = __shfl_xor(a1, off);
            const int   oi = __shfl_xor(ai, off);
            const float o2 = __shfl_xor(a2, off);
            if (o1 < a1 || (o1 == a1 && oi < ai)) { a2 = fminf(a1, o2); a1 = o1; ai = oi; }
            else                                  { a2 = fminf(a2, o1); }
        }
        if (g == 0) {
            smv1[w][nt * 16 + nidx] = a1;
            smv2[w][nt * 16 + nidx] = a2;
            smi1[w][nt * 16 + nidx] = ai;
        }
    }
    __syncthreads();
    if (tid < 64) {
        float b1 = smv1[0][tid], b2 = smv2[0][tid];
        int   bi = smi1[0][tid];
        #pragma unroll
        for (int ww = 1; ww < 8; ++ww) {
            const float c1 = smv1[ww][tid], c2 = smv2[ww][tid];
            const int   ci = smi1[ww][tid];
            if (c1 < b1 || (c1 == b1 && ci < bi)) { b2 = fminf(b1, c2); b1 = c1; bi = ci; }
            else                                  { b2 = fminf(b2, c1); }
        }
        idx[n0 + tid]  = bi;
        sidx[tid]      = bi;
        dmin[n0 + tid] = b1;
        if (b2 - b1 <= DELTA) flaglist[atomicAdd(nflag, 1)] = n0 + tid;
        atomicAdd(&counts[bi], 1);
        float contrib = znorm[tid] + b1;    // |z|^2 + (|q|^2 - 2 z.q) = |z-q|^2
        #pragma unroll
        for (int off = 32; off > 0; off >>= 1) contrib += __shfl_down(contrib, off);
        if (tid == 0) atomicAdd(lsum, contrib);
    }
    __syncthreads();

    // ---- Phase D: gather cb rows coalesced -> LDS bounce ----
    {
        const int l4 = t * 4;
        #pragma unroll
        for (int tt = 0; tt < 8; ++tt) {
            const int t2 = w * 8 + tt;
            const int k  = sidx[t2];
            const float4 v = *reinterpret_cast<const float4*>(cb + k * 256 + l4);
            *reinterpret_cast<float4*>(&qs[t2 * 257 + l4]) = v;
        }
    }
    __syncthreads();

    // ---- Phase E: coalesced out write ----
    {
        float* ob = out + (n0 >> 10) * 262144 + (n0 & 1023);
        #pragma unroll
        for (int j = 0; j < 32; ++j) {
            const int c = w * 32 + j;
            ob[c * 1024 + t] = qs[t * 257 + c];
        }
    }
}

// ---------------------------------------------------------------------------
// K3: exact fp32 rescan for flagged tokens + full fix-up. grid 256 x 512.
// 4 tokens/block; on argmin change: rewrite out row, counts, idx; always
// correct lsum to the exact distance (lsum += d_exact - dmin_approx).
// ---------------------------------------------------------------------------
__global__ __launch_bounds__(512) void vq_rescue(
    const float* __restrict__ z, const float* __restrict__ cb,
    const float* __restrict__ enorm, const int* __restrict__ nflag,
    const int* __restrict__ flaglist, int* __restrict__ idx,
    float* __restrict__ dmin, int* __restrict__ counts,
    float* __restrict__ lsum, float* __restrict__ out)
{
    __shared__ float zs[4][256];
    __shared__ float rv[4][512];
    __shared__ int   ri[4][512];
    const int tid = threadIdx.x;
    const int count = *nflag;
    for (int base = blockIdx.x * 4; base < count; base += 1024) {
        const int nt = min(4, count - base);
        __syncthreads();
        for (int tt = tid >> 8; tt < nt; tt += 2) {
            const int n = flaglist[base + tt];
            const int c = tid & 255;
            zs[tt][c] = z[(n >> 10) * 262144 + c * 1024 + (n & 1023)];
        }
        __syncthreads();
        float bv[4] = {1e30f, 1e30f, 1e30f, 1e30f};
        int   bi[4] = {0x7fffffff, 0x7fffffff, 0x7fffffff, 0x7fffffff};
        #pragma unroll
        for (int j = 0; j < 2; ++j) {
            const int k = tid * 2 + j;
            const float* er = cb + k * 256;
            float s0 = 0.f, s1 = 0.f, s2 = 0.f, s3 = 0.f;
            #pragma unroll 4
            for (int c = 0; c < 256; c += 4) {
                const float4 e4 = *reinterpret_cast<const float4*>(er + c);
                s0 = fmaf(e4.x, zs[0][c], fmaf(e4.y, zs[0][c+1], fmaf(e4.z, zs[0][c+2], fmaf(e4.w, zs[0][c+3], s0))));
                s1 = fmaf(e4.x, zs[1][c], fmaf(e4.y, zs[1][c+1], fmaf(e4.z, zs[1][c+2], fmaf(e4.w, zs[1][c+3], s1))));
                s2 = fmaf(e4.x, zs[2][c], fmaf(e4.y, zs[2][c+1], fmaf(e4.z, zs[2][c+2], fmaf(e4.w, zs[2][c+3], s2))));
                s3 = fmaf(e4.x, zs[3][c], fmaf(e4.y, zs[3][c+1], fmaf(e4.z, zs[3][c+2], fmaf(e4.w, zs[3][c+3], s3))));
            }
            const float en = enorm[k];
            float d;
            d = fmaf(-2.0f, s0, en); if (d < bv[0]) { bv[0] = d; bi[0] = k; }
            d = fmaf(-2.0f, s1, en); if (d < bv[1]) { bv[1] = d; bi[1] = k; }
            d = fmaf(-2.0f, s2, en); if (d < bv[2]) { bv[2] = d; bi[2] = k; }
            d = fmaf(-2.0f, s3, en); if (d < bv[3]) { bv[3] = d; bi[3] = k; }
        }
        #pragma unroll
        for (int tt = 0; tt < 4; ++tt) { rv[tt][tid] = bv[tt]; ri[tt][tid] = bi[tt]; }
        __syncthreads();
        const int wv = tid >> 6, lane = tid & 63;
        if (wv < nt) {
            float m = rv[wv][lane]; int mi = ri[wv][lane];
            #pragma unroll
            for (int s = 1; s < 8; ++s) {
                const float v = rv[wv][lane + s * 64]; const int ii = ri[wv][lane + s * 64];
                if (v < m || (v == m && ii < mi)) { m = v; mi = ii; }
            }
            #pragma unroll
            for (int off = 32; off > 0; off >>= 1) {
                const float ov = __shfl_down(m, off); const int oi = __shfl_down(mi, off);
                if (ov < m || (ov == m && oi < mi)) { m = ov; mi = oi; }
            }
            const float mB  = __shfl(m, 0);
            const int   miB = __shfl(mi, 0);
            const int n = flaglist[base + wv];
            const int kold = idx[n];
            if (lane == 0) {
                atomicAdd(lsum, mB - dmin[n]);       // exact-ify this token's loss term
                if (miB != kold) {
                    idx[n] = miB;
                    atomicSub(&counts[kold], 1);
                    atomicAdd(&counts[miB], 1);
                }
            }
            if (miB != kold) {                        // rewrite out row
                float* on = out + (n >> 10) * 262144 + (n & 1023);
                #pragma unroll
                for (int cc = 0; cc < 4; ++cc) {
                    const int c = cc * 64 + lane;
                    on[c * 1024] = cb[miB * 256 + c];
                }
            }
        }
    }
}

// ---------------------------------------------------------------------------
// K4: scalars. vq_loss = (1+BETA)*lsum/numel; perplexity from counts.
// ---------------------------------------------------------------------------
__global__ __launch_bounds__(256) void vq_finalize(
    const int* __restrict__ counts, const float* __restrict__ lsum,
    float* __restrict__ outs)
{
    __shared__ float ssum[4];
    const int tid = threadIdx.x;
    float local = 0.0f;
    #pragma unroll
    for (int k = tid; k < 1024; k += 256) {
        float p = (float)counts[k] * (1.0f / 32768.0f);
        p = fmaxf(p, 1e-10f);
        local += p * logf(p);
    }
    #pragma unroll
    for (int off = 32; off > 0; off >>= 1) local += __shfl_down(local, off);
    if ((tid & 63) == 0) ssum[tid >> 6] = local;
    __syncthreads();
    if (tid == 0) {
        const float ent = ssum[0] + ssum[1] + ssum[2] + ssum[3];
        outs[0] = lsum[0] * ((1.0f + BETA) / 8388608.0f);
        outs[1] = expf(-ent);
    }
}

extern "C" void kernel_launch(void* const* d_in, const int* in_sizes, int n_in,
                              void* d_out, int out_size, void* d_ws, size_t ws_size,
                              hipStream_t stream)
{
    const float* z  = (const float*)d_in[0];
    const float* cb = (const float*)d_in[1];
    float* out = (float*)d_out;

    char* ws = (char*)d_ws;
    _Float16* ehp    = (_Float16*)(ws);
    float*    enorm  = (float*)   (ws + 524288);
    int*      idx    = (int*)     (ws + 528384);
    float*    dmin   = (float*)   (ws + 659456);
    int*      counts = (int*)     (ws + 790528);
    float*    lsum   = (float*)   (ws + 794624);
    int*      nflag  = (int*)     (ws + 794688);
    int*      flag   = (int*)     (ws + 794752);

    vq_prep    <<<388, 256, 0, stream>>>(cb, ehp, enorm, counts, lsum, nflag);
    vq_main    <<<512, 512, 0, stream>>>(z, cb, ehp, enorm, out, idx, dmin,
                                         counts, lsum, nflag, flag);
    vq_rescue  <<<256, 512, 0, stream>>>(z, cb, enorm, nflag, flag, idx,
                                         dmin, counts, lsum, out);
    vq_finalize<<<1, 256, 0, stream>>>(counts, lsum, out + 8388608);
}